// Round 4
// baseline (183.953 us; speedup 1.0000x reference)
//
#include <hip/hip_runtime.h>
#include <math.h>

#define NROWS 8192
#define DIM   1024
#define BT    256              // tile edge
#define NCHUNK 32              // 8192 / 256 column chunks
#define NTRI  528              // 32*33/2 lower-triangle tiles
#define GRID  512              // 16 blocks take 2 tiles -> 2-round makespan
#define NKT   32               // 1024 / BK
#define BK    32

typedef __bf16 bf16x8 __attribute__((ext_vector_type(8)));
typedef float  f32x4  __attribute__((ext_vector_type(4)));

// fp32 -> bf16 (RNE)
__device__ __forceinline__ unsigned short f2bf(float f) {
    unsigned int u = __float_as_uint(f);
    u = (u + 0x7FFFu + ((u >> 16) & 1u)) >> 16;
    return (unsigned short)u;
}

__device__ __forceinline__ void gld16(const void* g, void* l) {
    __builtin_amdgcn_global_load_lds(
        (__attribute__((address_space(1))) void*)g,
        (__attribute__((address_space(3))) void*)l,
        16, 0, 0);
}

// DPP rotate-right by N within each 16-lane row
template<int N>
__device__ __forceinline__ float dppror(float v) {
    return __int_as_float(__builtin_amdgcn_update_dpp(
        0, __float_as_int(v), 0x120 + N, 0xF, 0xF, false));
}

__device__ __forceinline__ void t2push(float& a1, float& a2, float v) {
    float hi = fmaxf(a1, v);
    float lo = fminf(a1, v);
    a1 = hi;
    a2 = fmaxf(a2, lo);
}

__device__ __forceinline__ void t2merge(float& a1, float& a2, float b1, float b2) {
    float hi = fmaxf(a1, b1);
    float lo = fminf(a1, b1);
    a1 = hi;
    a2 = fmaxf(fmaxf(a2, b2), lo);
}

// ---------------- Kernel A: row L2-normalize, fp32 -> bf16 ----------------
__global__ __launch_bounds__(256) void knorm(const float* __restrict__ x,
                                             unsigned short* __restrict__ xn) {
    const int w = threadIdx.x >> 6, lane = threadIdx.x & 63;
    const int row = blockIdx.x * 4 + w;
    const float4* src = (const float4*)(x + (size_t)row * DIM);
    float4 v[4];
    float ss = 0.0f;
    #pragma unroll
    for (int i = 0; i < 4; i++) {
        v[i] = src[lane + 64 * i];
        ss += v[i].x * v[i].x + v[i].y * v[i].y + v[i].z * v[i].z + v[i].w * v[i].w;
    }
    #pragma unroll
    for (int d = 1; d < 64; d <<= 1) ss += __shfl_xor(ss, d);
    const float inv = 1.0f / fmaxf(sqrtf(ss), 1e-8f);
    unsigned short* dst = xn + (size_t)row * DIM;
    #pragma unroll
    for (int i = 0; i < 4; i++) {
        uint2 o;
        o.x = (unsigned)f2bf(v[i].x * inv) | ((unsigned)f2bf(v[i].y * inv) << 16);
        o.y = (unsigned)f2bf(v[i].z * inv) | ((unsigned)f2bf(v[i].w * inv) << 16);
        *(uint2*)(dst + (size_t)(lane + 64 * i) * 4) = o;
    }
}

// ------- Kernel B: symmetric 256x256-tile gram, 8 waves, BK=32,
// 3-buffer counted-vmcnt pipeline (stage kt+2 while computing kt),
// swizzled LDS (involution s = g ^ (r&3) ^ ((r>>2)&3)), fused top-2.
__global__ __launch_bounds__(512) void kgram(const unsigned short* __restrict__ xn,
                                             float2* __restrict__ top2) {
    // 3 x 32KB K-tile buffers (A 16KB | B 16KB), then reduce scratch
    __shared__ __align__(16) char smem[110592];
    float (*st2r)[256][2] = (float (*)[256][2])(smem + 98304);          // [4][256][2]
    float (*st2c)[256][2] = (float (*)[256][2])(smem + 98304 + 8192);   // [2][256][2]

    const int t = threadIdx.x;
    const int lane = t & 63;
    const int w = t >> 6;            // 0..7
    const int wr = w >> 2, wc = w & 3;
    const int g = lane >> 4, c = lane & 15;

    // fragment LDS byte offset (row-block-relative); swizzle folded in.
    // row r = <rowblock>*16 + c, chunk col g -> stored chunk s = g ^ (c&3) ^ ((c>>2)&3)
    const int LA = c * 64 + (((g ^ (c & 3) ^ ((c >> 2) & 3)) & 3) << 4);

    // staging constants: thread covers chunks q0,q1 of each 1024-chunk tile
    const int q0 = t, q1 = 512 + t;
    const int r0 = q0 >> 2, g0 = (q0 & 3) ^ (r0 & 3) ^ ((r0 >> 2) & 3);
    const int r1 = q1 >> 2, g1 = (q1 & 3) ^ (r1 & 3) ^ ((r1 >> 2) & 3);

    const int bswz = (blockIdx.x & 7) * (GRID / 8) + (blockIdx.x >> 3);

    for (int tix = bswz; tix < NTRI; tix += GRID) {
        int by = (int)((sqrtf(8.0f * (float)tix + 1.0f) - 1.0f) * 0.5f);
        while ((by + 1) * (by + 2) / 2 <= tix) by++;
        while (by * (by + 1) / 2 > tix) by--;
        const int bx = tix - by * (by + 1) / 2;
        const bool diagTile = (bx == by);

        const unsigned short* sA0 = xn + (size_t)(by * BT + r0) * DIM + g0 * 8;
        const unsigned short* sA1 = xn + (size_t)(by * BT + r1) * DIM + g1 * 8;
        const unsigned short* sB0 = xn + (size_t)(bx * BT + r0) * DIM + g0 * 8;
        const unsigned short* sB1 = xn + (size_t)(bx * BT + r1) * DIM + g1 * 8;

        f32x4 acc[8][4];
        #pragma unroll
        for (int m = 0; m < 8; m++)
            #pragma unroll
            for (int n = 0; n < 4; n++) acc[m][n] = (f32x4)0.0f;

        auto STAGE = [&](int b, int kt) {
            char* base = smem + b * 32768;
            gld16(sA0 + kt * BK, base + q0 * 16);
            gld16(sA1 + kt * BK, base + q1 * 16);
            gld16(sB0 + kt * BK, base + 16384 + q0 * 16);
            gld16(sB1 + kt * BK, base + 16384 + q1 * 16);
        };

        // prologue: tiles 0,1 staged; wait tile 0 (4 newest outstanding = tile1)
        STAGE(0, 0);
        STAGE(1, 1);
        asm volatile("s_waitcnt vmcnt(4)" ::: "memory");
        __builtin_amdgcn_s_barrier();
        asm volatile("" ::: "memory");
        __builtin_amdgcn_sched_barrier(0);

        int cur = 0;
        #pragma unroll 1
        for (int kt = 0; kt < NKT; ++kt) {
            if (kt + 2 < NKT) {
                int nb = cur + 2; if (nb >= 3) nb -= 3;
                STAGE(nb, kt + 2);
            }
            const char* Ab = smem + cur * 32768 + wr * 8192 + LA;
            const char* Bb = smem + cur * 32768 + 16384 + wc * 4096 + LA;
            bf16x8 b0 = *(const bf16x8*)(Bb + 0 * 1024);
            bf16x8 b1 = *(const bf16x8*)(Bb + 1 * 1024);
            bf16x8 b2 = *(const bf16x8*)(Bb + 2 * 1024);
            bf16x8 b3 = *(const bf16x8*)(Bb + 3 * 1024);
            #pragma unroll
            for (int ph = 0; ph < 2; ++ph) {
                bf16x8 a0 = *(const bf16x8*)(Ab + (ph * 4 + 0) * 1024);
                bf16x8 a1 = *(const bf16x8*)(Ab + (ph * 4 + 1) * 1024);
                bf16x8 a2 = *(const bf16x8*)(Ab + (ph * 4 + 2) * 1024);
                bf16x8 a3 = *(const bf16x8*)(Ab + (ph * 4 + 3) * 1024);
                asm volatile("s_waitcnt lgkmcnt(0)" ::: "memory");
                __builtin_amdgcn_sched_barrier(0);
                __builtin_amdgcn_s_setprio(1);
                acc[ph*4+0][0] = __builtin_amdgcn_mfma_f32_16x16x32_bf16(a0, b0, acc[ph*4+0][0], 0, 0, 0);
                acc[ph*4+0][1] = __builtin_amdgcn_mfma_f32_16x16x32_bf16(a0, b1, acc[ph*4+0][1], 0, 0, 0);
                acc[ph*4+0][2] = __builtin_amdgcn_mfma_f32_16x16x32_bf16(a0, b2, acc[ph*4+0][2], 0, 0, 0);
                acc[ph*4+0][3] = __builtin_amdgcn_mfma_f32_16x16x32_bf16(a0, b3, acc[ph*4+0][3], 0, 0, 0);
                acc[ph*4+1][0] = __builtin_amdgcn_mfma_f32_16x16x32_bf16(a1, b0, acc[ph*4+1][0], 0, 0, 0);
                acc[ph*4+1][1] = __builtin_amdgcn_mfma_f32_16x16x32_bf16(a1, b1, acc[ph*4+1][1], 0, 0, 0);
                acc[ph*4+1][2] = __builtin_amdgcn_mfma_f32_16x16x32_bf16(a1, b2, acc[ph*4+1][2], 0, 0, 0);
                acc[ph*4+1][3] = __builtin_amdgcn_mfma_f32_16x16x32_bf16(a1, b3, acc[ph*4+1][3], 0, 0, 0);
                acc[ph*4+2][0] = __builtin_amdgcn_mfma_f32_16x16x32_bf16(a2, b0, acc[ph*4+2][0], 0, 0, 0);
                acc[ph*4+2][1] = __builtin_amdgcn_mfma_f32_16x16x32_bf16(a2, b1, acc[ph*4+2][1], 0, 0, 0);
                acc[ph*4+2][2] = __builtin_amdgcn_mfma_f32_16x16x32_bf16(a2, b2, acc[ph*4+2][2], 0, 0, 0);
                acc[ph*4+2][3] = __builtin_amdgcn_mfma_f32_16x16x32_bf16(a2, b3, acc[ph*4+2][3], 0, 0, 0);
                acc[ph*4+3][0] = __builtin_amdgcn_mfma_f32_16x16x32_bf16(a3, b0, acc[ph*4+3][0], 0, 0, 0);
                acc[ph*4+3][1] = __builtin_amdgcn_mfma_f32_16x16x32_bf16(a3, b1, acc[ph*4+3][1], 0, 0, 0);
                acc[ph*4+3][2] = __builtin_amdgcn_mfma_f32_16x16x32_bf16(a3, b2, acc[ph*4+3][2], 0, 0, 0);
                acc[ph*4+3][3] = __builtin_amdgcn_mfma_f32_16x16x32_bf16(a3, b3, acc[ph*4+3][3], 0, 0, 0);
                __builtin_amdgcn_s_setprio(0);
                __builtin_amdgcn_sched_barrier(0);
            }
            if (kt + 1 < NKT) {
                if (kt + 2 < NKT) asm volatile("s_waitcnt vmcnt(4)" ::: "memory");
                else              asm volatile("s_waitcnt vmcnt(0)" ::: "memory");
                __builtin_amdgcn_s_barrier();
                asm volatile("" ::: "memory");
                __builtin_amdgcn_sched_barrier(0);
            }
            cur = cur + 1; if (cur >= 3) cur -= 3;
        }

        // ---- per-row top-2 (rows of by-block) ----
        #pragma unroll
        for (int m = 0; m < 8; m++) {
            #pragma unroll
            for (int rr = 0; rr < 4; rr++) {
                const int lrow = wr * 128 + m * 16 + g * 4 + rr;
                float a1 = -1e30f, a2 = -1e30f;
                #pragma unroll
                for (int n = 0; n < 4; n++) {
                    float v = acc[m][n][rr];
                    if (diagTile && (wc * 64 + n * 16 + c) == lrow) v = -2.0f;
                    t2push(a1, a2, v);
                }
                { float b1 = dppror<1>(a1), b2 = dppror<1>(a2); t2merge(a1, a2, b1, b2); }
                { float b1 = dppror<2>(a1), b2 = dppror<2>(a2); t2merge(a1, a2, b1, b2); }
                { float b1 = dppror<4>(a1), b2 = dppror<4>(a2); t2merge(a1, a2, b1, b2); }
                { float b1 = dppror<8>(a1), b2 = dppror<8>(a2); t2merge(a1, a2, b1, b2); }
                if (c == 0) { st2r[wc][lrow][0] = a1; st2r[wc][lrow][1] = a2; }
            }
        }
        // ---- per-col top-2 (rows of bx-block via symmetry) ----
        if (!diagTile) {
            #pragma unroll
            for (int n = 0; n < 4; n++) {
                const int lcol = wc * 64 + n * 16 + c;
                float a1 = -1e30f, a2 = -1e30f;
                #pragma unroll
                for (int m = 0; m < 8; m++)
                    #pragma unroll
                    for (int rr = 0; rr < 4; rr++)
                        t2push(a1, a2, acc[m][n][rr]);
                #pragma unroll
                for (int d = 16; d < 64; d <<= 1) {
                    float b1 = __shfl_xor(a1, d);
                    float b2 = __shfl_xor(a2, d);
                    t2merge(a1, a2, b1, b2);
                }
                if (g == 0) { st2c[wr][lcol][0] = a1; st2c[wr][lcol][1] = a2; }
            }
        }
        __syncthreads();
        if (t < 256) {
            float a1 = st2r[0][t][0], a2 = st2r[0][t][1];
            t2merge(a1, a2, st2r[1][t][0], st2r[1][t][1]);
            t2merge(a1, a2, st2r[2][t][0], st2r[2][t][1]);
            t2merge(a1, a2, st2r[3][t][0], st2r[3][t][1]);
            top2[(size_t)(by * BT + t) * NCHUNK + bx] = make_float2(a1, a2);
        } else if (!diagTile) {
            const int tc = t - 256;
            float a1 = st2c[0][tc][0], a2 = st2c[0][tc][1];
            t2merge(a1, a2, st2c[1][tc][0], st2c[1][tc][1]);
            top2[(size_t)(bx * BT + tc) * NCHUNK + by] = make_float2(a1, a2);
        }
        __syncthreads();
    }
}

// ------- Kernel C: one wave per row; lanes 0..31 <-> chunks; loss/gate -------
__global__ __launch_bounds__(256) void kloss(const float2* __restrict__ top2,
                                             float2* __restrict__ partials) {
    const int t = threadIdx.x;
    const int w = t >> 6, lane = t & 63;
    const int row = blockIdx.x * 4 + w;   // 2048 blocks x 4 waves
    float a1 = -1e30f, a2 = -1e30f;
    if (lane < NCHUNK) {
        float2 q = top2[(size_t)row * NCHUNK + lane];
        a1 = q.x; a2 = q.y;
    }
    #pragma unroll
    for (int d = 1; d < 64; d <<= 1) {
        float b1 = __shfl_xor(a1, d);
        float b2 = __shfl_xor(a2, d);
        t2merge(a1, a2, b1, b2);
    }
    __shared__ float2 wsum[4];
    if (lane == 0) {
        float slg = 0.0f, sg = 0.0f;
        float vs[2] = {a1, a2};
        #pragma unroll
        for (int i = 0; i < 2; i++) {
            float dd = sqrtf(fmaxf(2.0f - 2.0f * vs[i], 0.0f));
            float loss = -logf(dd + 1e-8f);
            float gate = 1.0f / (1.0f + expf(-(loss - 0.5f) * 10.0f));
            slg += loss * gate;
            sg += gate;
        }
        wsum[w] = make_float2(slg, sg);
    }
    __syncthreads();
    if (t == 0) {
        float a = 0.0f, b = 0.0f;
        #pragma unroll
        for (int i = 0; i < 4; i++) { a += wsum[i].x; b += wsum[i].y; }
        partials[blockIdx.x] = make_float2(a, b);
    }
}

// ---------------- Kernel D: final scalar over 2048 partials ----------------
__global__ __launch_bounds__(256) void kfinal(const float2* __restrict__ partials,
                                              float* __restrict__ out) {
    const int t = threadIdx.x;
    float a = 0.0f, b = 0.0f;
    for (int i = t; i < 2048; i += 256) {
        float2 p = partials[i];
        a += p.x; b += p.y;
    }
    #pragma unroll
    for (int d = 1; d < 64; d <<= 1) {
        a += __shfl_xor(a, d);
        b += __shfl_xor(b, d);
    }
    __shared__ float2 ws4[4];
    if ((t & 63) == 0) ws4[t >> 6] = make_float2(a, b);
    __syncthreads();
    if (t == 0) {
        float A = 0.0f, Bb = 0.0f;
        #pragma unroll
        for (int i = 0; i < 4; i++) { A += ws4[i].x; Bb += ws4[i].y; }
        float wm = A / 16384.0f;
        float gm = A / fmaxf(Bb, 1.0f);
        out[0] = 0.5f * wm + 0.5f * gm;
    }
}

extern "C" void kernel_launch(void* const* d_in, const int* in_sizes, int n_in,
                              void* d_out, int out_size, void* d_ws, size_t ws_size,
                              hipStream_t stream) {
    const float* x = (const float*)d_in[0];
    unsigned short* xn = (unsigned short*)d_ws;                              // 16 MB
    float2* top2 = (float2*)((char*)d_ws + (size_t)16 * 1024 * 1024);        // 2 MB
    float2* partials = (float2*)((char*)d_ws + (size_t)20 * 1024 * 1024);    // 16 KB
    float* out = (float*)d_out;

    knorm<<<NROWS / 4, 256, 0, stream>>>(x, xn);
    kgram<<<GRID, 512, 0, stream>>>(xn, top2);
    kloss<<<2048, 256, 0, stream>>>(top2, partials);
    kfinal<<<1, 256, 0, stream>>>(partials, out);
}